// Round 2
// baseline (523.561 us; speedup 1.0000x reference)
//
#include <hip/hip_runtime.h>
#include <hip/hip_bf16.h>

// Problem constants (fixed by the reference).
constexpr int T  = 4096;   // time / contraction dim (K)
constexpr int Bb = 8;      // batch
constexpr int C  = 512;    // channels (N)
constexpr int S  = 2048;   // groups (M)
constexpr int BC = Bb * C; // 4096, stride of a t-row in x and an s-row in out

constexpr int KSPLIT = 4;        // split-K factor
constexpr int KT     = T / KSPLIT;  // 1024 t per block

typedef __bf16 bf16x8 __attribute__((ext_vector_type(8)));
typedef float  f32x16 __attribute__((ext_vector_type(16)));

__device__ inline __bf16 f2b(float f) {
    union { __hip_bfloat16 h; __bf16 b; } u;
    u.h = __float2bfloat16(f);   // RNE f32->bf16
    return u.b;
}

// Zero rows 1..S of out (atomic accumulation target) and fill row 0 with
// the leftmost-group embedding broadcast over batch. float4 grid-stride.
__global__ void init_out(const float* __restrict__ left, float* __restrict__ out) {
    const size_t total4 = (size_t)(S + 1) * BC / 4;
    float4* o4 = (float4*)out;
    size_t i = (size_t)blockIdx.x * blockDim.x + threadIdx.x;
    const size_t stride = (size_t)gridDim.x * blockDim.x;
    for (; i < total4; i += stride) {
        if (i < BC / 4) {
            const int c = ((int)i * 4) & (C - 1);
            o4[i] = make_float4(left[c], left[c + 1], left[c + 2], left[c + 3]);
        } else {
            o4[i] = make_float4(0.f, 0.f, 0.f, 0.f);
        }
    }
}

// Per-b GEMM with split-K: D[s,c] += sum_{t in chunk} mask[b,t,s] * x[t,b,c],
// atomically accumulated into out[(s+1),b,c].
// Block = 256 threads = 4 waves (2x2), block tile 128(s) x 128(c), K-chunk 1024.
// Wave tile 64x64 = 2x2 fragments of v_mfma_f32_32x32x16_bf16.
// Direct global->fragment loads (coalesced 128B runs along s for mask, along c
// for x), fp32->bf16 conversion in registers. Grid = KSPLIT*B*4*16 = 2048
// blocks -> ~7 blocks/CU resident (VGPR-limited), vs 2/CU before split-K.
__global__ __launch_bounds__(256, 4) void ds_gemm(
    const float* __restrict__ x,
    const float* __restrict__ mask,
    float* __restrict__ out)
{
    const int bid = blockIdx.x;
    const int mt  = bid & 15;         // s-tile (fastest: neighbors share x panel / L2)
    const int nt  = (bid >> 4) & 3;   // c-tile
    const int b   = (bid >> 6) & 7;   // batch
    const int kc  = bid >> 9;         // k-chunk (slowest: atomic writers separated in time)

    const int tid  = threadIdx.x;
    const int lane = tid & 63;
    const int wave = tid >> 6;        // 0..3
    const int wm = wave >> 1, wn = wave & 1;

    const int lm = lane & 31;         // row/col within a 32x32 fragment
    const int kg = lane >> 5;         // k-half select (0/1)

    const int s_w = mt * 128 + wm * 64;
    const int c_w = nt * 128 + wn * 64;
    const int t0b = kc * KT;

    const float* maskB = mask + (size_t)b * T * S;
    // A fragment: element i of frag m2 is pa[i*S + m2*32]
    const float* pa = maskB + (size_t)(t0b + kg * 8) * S + (s_w + lm);
    // B fragment: element i of frag n2 is pb[i*BC + n2*32]
    const float* pb = x + (size_t)(t0b + kg * 8) * BC + b * C + (c_w + lm);

    f32x16 acc[2][2] = {};
    bf16x8 Ac[2], Bc[2], An[2], Bn[2];

#define LOAD_FRAGS(Af, Bf, PA, PB)                                   \
    {                                                                \
        _Pragma("unroll") for (int m2 = 0; m2 < 2; ++m2) {           \
            _Pragma("unroll") for (int i = 0; i < 8; ++i)            \
                Af[m2][i] = f2b((PA)[(size_t)i * S + m2 * 32]);      \
        }                                                            \
        _Pragma("unroll") for (int n2 = 0; n2 < 2; ++n2) {           \
            _Pragma("unroll") for (int i = 0; i < 8; ++i)            \
                Bf[n2][i] = f2b((PB)[(size_t)i * BC + n2 * 32]);     \
        }                                                            \
    }

#define DO_MFMA(Af, Bf)                                              \
    {                                                                \
        _Pragma("unroll") for (int m2 = 0; m2 < 2; ++m2)             \
        _Pragma("unroll") for (int n2 = 0; n2 < 2; ++n2)             \
            acc[m2][n2] = __builtin_amdgcn_mfma_f32_32x32x16_bf16(   \
                Af[m2], Bf[n2], acc[m2][n2], 0, 0, 0);               \
    }

    // Prologue: fragments for first K=16 of this chunk.
    LOAD_FRAGS(Ac, Bc, pa, pb);

    // Each iteration consumes 32 t (two K=16 fragment sets), register ping-pong.
    for (int t0 = 0; t0 < KT - 32; t0 += 32) {
        LOAD_FRAGS(An, Bn, pa + (size_t)16 * S, pb + (size_t)16 * BC);
        DO_MFMA(Ac, Bc);
        pa += (size_t)32 * S;
        pb += (size_t)32 * BC;
        LOAD_FRAGS(Ac, Bc, pa, pb);
        DO_MFMA(An, Bn);
    }
    // Epilogue: pa/pb at t = KT-32 of the chunk; Ac holds [KT-32, KT-16).
    LOAD_FRAGS(An, Bn, pa + (size_t)16 * S, pb + (size_t)16 * BC);
    DO_MFMA(Ac, Bc);
    DO_MFMA(An, Bn);

#undef LOAD_FRAGS
#undef DO_MFMA

    // Epilogue: atomic accumulate (4 k-chunks target each element).
    // C/D layout (HW-verified): col = lane&31, row = (r&3)+8*(r>>2)+4*(lane>>5).
    float* outp = out + BC;   // skip the leftmost row
#pragma unroll
    for (int m2 = 0; m2 < 2; ++m2) {
#pragma unroll
        for (int n2 = 0; n2 < 2; ++n2) {
#pragma unroll
            for (int r = 0; r < 16; ++r) {
                const int row  = (r & 3) + 8 * (r >> 2) + 4 * kg;
                const int srow = s_w + m2 * 32 + row;
                const int ccol = c_w + n2 * 32 + lm;
                atomicAdd(&outp[(size_t)srow * BC + b * C + ccol], acc[m2][n2][r]);
            }
        }
    }
}

extern "C" void kernel_launch(void* const* d_in, const int* in_sizes, int n_in,
                              void* d_out, int out_size, void* d_ws, size_t ws_size,
                              hipStream_t stream) {
    const float* x    = (const float*)d_in[0];  // [T,B,C] fp32
    const float* mask = (const float*)d_in[1];  // [B,T,S] fp32
    // d_in[2] = size_of_groups (int64) — unused by the 'average' reference path
    const float* left = (const float*)d_in[3];  // [1,1,C] fp32
    float* out = (float*)d_out;                 // [S+1,B,C] fp32

    init_out<<<2048, 256, 0, stream>>>(left, out);
    ds_gemm<<<KSPLIT * Bb * (S / 128) * (C / 128), 256, 0, stream>>>(x, mask, out);
}

// Round 3
// 309.757 us; speedup vs baseline: 1.6902x; 1.6902x over previous
//
#include <hip/hip_runtime.h>
#include <hip/hip_bf16.h>

// Problem constants (fixed by the reference).
constexpr int T  = 4096;   // contraction dim (K = t)
constexpr int Bb = 8;      // batch
constexpr int C  = 512;    // channels (N)
constexpr int S  = 2048;   // groups (M)
constexpr int BC = Bb * C; // 4096 floats: t-row stride of x, s-row stride of out

constexpr int BK = 32;        // K-tile staged per iteration
constexpr int NK = T / BK;    // 128 iterations

typedef __bf16 bf16x8 __attribute__((ext_vector_type(8)));
typedef float  f32x16 __attribute__((ext_vector_type(16)));
typedef float  f32x4  __attribute__((ext_vector_type(4)));

// pack two f32 -> one dword of 2x bf16 (lo = first, hi = second), RNE.
__device__ inline unsigned pk2(float lo, float hi) {
    union { __hip_bfloat16 h; unsigned short u; } a, b;
    a.h = __float2bfloat16(lo);
    b.h = __float2bfloat16(hi);
    return ((unsigned)b.u << 16) | (unsigned)a.u;
}

// 16B-slot swizzle: bijective within each 32-slot group; makes the strided
// staging writes bank-uniform while keeping fragment reads conflict-free.
__device__ inline int slot16(int s) { return s ^ ((s >> 2) & 7); }

// out[0,b,c] = leftmost[c]
__global__ void left_fill(const float* __restrict__ left, float* __restrict__ out) {
    int i = blockIdx.x * blockDim.x + threadIdx.x;   // 0..BC-1
    if (i < BC) out[i] = left[i & (C - 1)];
}

// Per-b GEMM: out[(s+1),b,c] = sum_t mask[b,t,s] * x[t,b,c].
// Block 256 thr = 4 waves (2x2), tile 128(s) x 128(c), K-tile 32, dbuf LDS.
// LDS layout per operand tile: bf16, addr = oct(t)*2048B + slot16(s)*16B + (t&7)*2B
// -> one ds_read_b128 per 32x32x16 fragment. Staging: threads 0-127 stage the
// mask tile, 128-255 the x tile; each thread loads 8 rows x float4, packs to
// bf16 pairs (the k-pair transpose), writes 4x ds_write_b128.
__global__ __launch_bounds__(256, 2) void ds_gemm(
    const float* __restrict__ x,
    const float* __restrict__ mask,
    float* __restrict__ out)
{
    __shared__ __align__(16) unsigned char smem[32768];  // [A0|A1|B0|B1], 8KB each

    const int bid = blockIdx.x;
    const int mt  = bid & 15;        // s-tile (fastest)
    const int nt  = (bid >> 4) & 3;  // c-tile
    const int b   = bid >> 6;        // batch (slowest: 40MB/b working set fits L3)

    const int tid  = threadIdx.x;
    const int lane = tid & 63;
    const int wave = tid >> 6;
    const int wm = wave >> 1, wn = wave & 1;
    const int lm = lane & 31;
    const int kg = lane >> 5;

    // ---------------- staging role ----------------
    const int  ii     = tid & 127;
    const int  sg     = ii & 31;       // 4-wide column group within the 128-wide tile
    const int  tg     = ii >> 5;       // t-oct 0..3 within the K-tile
    const bool stageB = (tid >= 128);

    const float* gsrc;
    size_t grow;  // floats between consecutive t rows
    if (!stageB) {
        gsrc = mask + (size_t)b * T * S + (size_t)(tg * 8) * S + mt * 128 + sg * 4;
        grow = S;
    } else {
        gsrc = x + (size_t)(tg * 8) * BC + b * C + nt * 128 + sg * 4;
        grow = BC;
    }
    const size_t gtile = grow * BK;   // advance per K-tile

    int waddr[4];
#pragma unroll
    for (int j = 0; j < 4; ++j)
        waddr[j] = (stageB ? 16384 : 0) + tg * 2048 + slot16(sg * 4 + j) * 16;

    // ---------------- fragment read addresses ----------------
    int raddrA[2][2], raddrB[2][2];
#pragma unroll
    for (int kk = 0; kk < 2; ++kk)
#pragma unroll
        for (int m2 = 0; m2 < 2; ++m2) {
            raddrA[kk][m2] = (kk * 2 + kg) * 2048 + slot16(wm * 64 + m2 * 32 + lm) * 16;
            raddrB[kk][m2] = 16384 + (kk * 2 + kg) * 2048 + slot16(wn * 64 + m2 * 32 + lm) * 16;
        }

    f32x16 acc[2][2] = {};
    f32x4  L[8];

#define LOAD_TILE(k)                                                        \
    {                                                                       \
        const float* p_ = gsrc + (size_t)(k) * gtile;                       \
        _Pragma("unroll") for (int r = 0; r < 8; ++r)                       \
            L[r] = *(const f32x4*)(p_ + (size_t)r * grow);                  \
    }

#define WRITE_TILE(buf)                                                     \
    {                                                                       \
        const int boff_ = (buf) * 8192;                                     \
        _Pragma("unroll") for (int j = 0; j < 4; ++j) {                     \
            uint4 w_;                                                       \
            w_.x = pk2(L[0][j], L[1][j]);                                   \
            w_.y = pk2(L[2][j], L[3][j]);                                   \
            w_.z = pk2(L[4][j], L[5][j]);                                   \
            w_.w = pk2(L[6][j], L[7][j]);                                   \
            *(uint4*)(smem + boff_ + waddr[j]) = w_;                        \
        }                                                                   \
    }

#define COMPUTE(buf)                                                        \
    {                                                                       \
        const int boff_ = (buf) * 8192;                                     \
        _Pragma("unroll") for (int kk = 0; kk < 2; ++kk) {                  \
            bf16x8 a0_ = *(const bf16x8*)(smem + boff_ + raddrA[kk][0]);    \
            bf16x8 a1_ = *(const bf16x8*)(smem + boff_ + raddrA[kk][1]);    \
            bf16x8 b0_ = *(const bf16x8*)(smem + boff_ + raddrB[kk][0]);    \
            bf16x8 b1_ = *(const bf16x8*)(smem + boff_ + raddrB[kk][1]);    \
            acc[0][0] = __builtin_amdgcn_mfma_f32_32x32x16_bf16(a0_, b0_, acc[0][0], 0, 0, 0); \
            acc[0][1] = __builtin_amdgcn_mfma_f32_32x32x16_bf16(a0_, b1_, acc[0][1], 0, 0, 0); \
            acc[1][0] = __builtin_amdgcn_mfma_f32_32x32x16_bf16(a1_, b0_, acc[1][0], 0, 0, 0); \
            acc[1][1] = __builtin_amdgcn_mfma_f32_32x32x16_bf16(a1_, b1_, acc[1][1], 0, 0, 0); \
        }                                                                   \
    }

    // Prologue: stage tile 0.
    LOAD_TILE(0);
    WRITE_TILE(0);
    __syncthreads();

    for (int k = 0; k < NK; ++k) {
        if (k + 1 < NK) LOAD_TILE(k + 1);   // issue early; consumed after compute
        COMPUTE(k & 1);
        if (k + 1 < NK) {
            __syncthreads();                 // all reads of buf[(k+1)&1] (prev iter) done
            WRITE_TILE((k + 1) & 1);         // vmcnt wait lands here, hidden under MFMA
            __syncthreads();                 // staged tile visible before next compute
        }
    }

#undef LOAD_TILE
#undef WRITE_TILE
#undef COMPUTE

    // Epilogue. C/D layout (HW-verified): col = lane&31, row = (r&3)+8*(r>>2)+4*(lane>>5).
    const int s_w = mt * 128 + wm * 64;
    const int c_w = nt * 128 + wn * 64;
    float* outp = out + BC;   // skip leftmost row
#pragma unroll
    for (int m2 = 0; m2 < 2; ++m2) {
#pragma unroll
        for (int n2 = 0; n2 < 2; ++n2) {
#pragma unroll
            for (int r = 0; r < 16; ++r) {
                const int row  = (r & 3) + 8 * (r >> 2) + 4 * kg;
                const int srow = s_w + m2 * 32 + row;
                const int ccol = c_w + n2 * 32 + lm;
                outp[(size_t)srow * BC + b * C + ccol] = acc[m2][n2][r];
            }
        }
    }
}

extern "C" void kernel_launch(void* const* d_in, const int* in_sizes, int n_in,
                              void* d_out, int out_size, void* d_ws, size_t ws_size,
                              hipStream_t stream) {
    const float* x    = (const float*)d_in[0];  // [T,B,C] fp32
    const float* mask = (const float*)d_in[1];  // [B,T,S] fp32
    // d_in[2] = size_of_groups (int64) — unused by the 'average' reference path
    const float* left = (const float*)d_in[3];  // [1,1,C] fp32
    float* out = (float*)d_out;                 // [S+1,B,C] fp32

    left_fill<<<BC / 256, 256, 0, stream>>>(left, out);
    ds_gemm<<<Bb * (S / 128) * (C / 128), 256, 0, stream>>>(x, mask, out);
}

// Round 4
// 160.770 us; speedup vs baseline: 3.2566x; 1.9267x over previous
//
#include <hip/hip_runtime.h>
#include <hip/hip_bf16.h>

// Problem constants (fixed by the reference).
constexpr int T  = 4096;   // contraction dim (K = t)
constexpr int Bb = 8;      // batch
constexpr int C  = 512;    // channels (N)
constexpr int S  = 2048;   // groups (M)
constexpr int BC = Bb * C; // 4096 floats: t-row stride of x, s-row stride of out

constexpr int BK = 32;        // K-tile staged per iteration
constexpr int NK = T / BK;    // 128 iterations

typedef __bf16 bf16x8 __attribute__((ext_vector_type(8)));
typedef float  f32x16 __attribute__((ext_vector_type(16)));
typedef float  f32x4  __attribute__((ext_vector_type(4)));

// pack two f32 -> one dword of 2x bf16 (lo = first, hi = second), RNE.
__device__ inline unsigned pk2(float lo, float hi) {
    union { __hip_bfloat16 h; unsigned short u; } a, b;
    a.h = __float2bfloat16(lo);
    b.h = __float2bfloat16(hi);
    return ((unsigned)b.u << 16) | (unsigned)a.u;
}

// 16B-slot swizzle, bijective within each 32-slot group. Read-side bank
// pattern: lanes lm=0..7 -> bank starts {0,20,8,28,16,4,24,12} -> the 8
// 16B-granules cover all 32 banks exactly once (conflict-free b128 reads).
__device__ inline int slot16(int s) { return s ^ ((s >> 2) & 7); }

// out[0,b,c] = leftmost[c]
__global__ void left_fill(const float* __restrict__ left, float* __restrict__ out) {
    int i = blockIdx.x * blockDim.x + threadIdx.x;   // 0..BC-1
    if (i < BC) out[i] = left[i & (C - 1)];
}

// Per-b GEMM: out[(s+1),b,c] = sum_t mask[b,t,s] * x[t,b,c].
// Block 512 thr = 8 waves (2m x 4n), tile 128(s) x 128(c), K-tile 32, dbuf LDS.
// 512 blocks -> 2 blocks/CU -> 16 waves/CU = 4 waves/SIMD.
// Loop: W(k)[vmcnt wait] -> issue loads(k+1) -> barrier -> COMPUTE(k):
// the global loads get a full iteration of latency cover, one barrier/iter.
// LDS (bf16): per operand per buf: oct(t/8)*2048B + slot16(col)*16B + (t&7)*2B
// -> one ds_read_b128 per 32x32x16 fragment operand.
__global__ __launch_bounds__(512, 4) void ds_gemm(
    const float* __restrict__ x,
    const float* __restrict__ mask,
    float* __restrict__ out)
{
    __shared__ __align__(16) unsigned char smem[32768];  // 2 bufs x (8KB A | 8KB B)

    const int bid = blockIdx.x;
    const int mt  = bid & 15;        // s-tile (fastest)
    const int nt  = (bid >> 4) & 3;  // c-tile
    const int b   = bid >> 6;        // batch (slowest)

    const int tid  = threadIdx.x;
    const int lane = tid & 63;
    const int wave = tid >> 6;       // 0..7
    const int wm = wave >> 2;        // s-half   (0..1)
    const int wn = wave & 3;         // c-quarter (0..3)
    const int lm = lane & 31;
    const int kg = lane >> 5;

    // ---------------- staging role: threads 0-255 stage A(mask), 256-511 B(x)
    const int  ii  = tid & 255;
    const int  sg  = ii & 31;        // 4-wide col group within 128-wide tile
    const int  tq  = ii >> 5;        // t-quad 0..7 (4 t-rows each)
    const bool stB = (tid >= 256);

    const float* gsrc = stB
        ? x    + (size_t)(tq * 4) * BC + b * C + nt * 128 + sg * 4
        : mask + (size_t)b * T * S + (size_t)(tq * 4) * S + mt * 128 + sg * 4;
    const size_t grow  = stB ? (size_t)BC : (size_t)S;  // floats per t-row
    const size_t gstep = grow * BK;                      // advance per K-tile

    const int wbase = (stB ? 8192 : 0) + (tq >> 1) * 2048 + (tq & 1) * 8;
    int waddr[4];
#pragma unroll
    for (int j = 0; j < 4; ++j)
        waddr[j] = wbase + slot16(sg * 4 + j) * 16;

    // ---------------- fragment read addresses (oct = kk*2 + kg)
    int raddrA[2][2], raddrB[2];
#pragma unroll
    for (int kk = 0; kk < 2; ++kk) {
#pragma unroll
        for (int m2 = 0; m2 < 2; ++m2)
            raddrA[kk][m2] = (kk * 2 + kg) * 2048 + slot16(wm * 64 + m2 * 32 + lm) * 16;
        raddrB[kk] = 8192 + (kk * 2 + kg) * 2048 + slot16(wn * 32 + lm) * 16;
    }

    f32x16 acc[2] = {};
    f32x4  L[4];

#define LOAD_TILE(k)                                                        \
    {                                                                       \
        const float* p_ = gsrc + (size_t)(k) * gstep;                       \
        _Pragma("unroll") for (int r = 0; r < 4; ++r)                       \
            L[r] = *(const f32x4*)(p_ + (size_t)r * grow);                  \
    }

#define WRITE_TILE(buf)                                                     \
    {                                                                       \
        const int boff_ = (buf) * 16384;                                    \
        _Pragma("unroll") for (int j = 0; j < 4; ++j) {                     \
            uint2 w_;                                                       \
            w_.x = pk2(L[0][j], L[1][j]);                                   \
            w_.y = pk2(L[2][j], L[3][j]);                                   \
            *(uint2*)(smem + boff_ + waddr[j]) = w_;                        \
        }                                                                   \
    }

#define COMPUTE(buf)                                                        \
    {                                                                       \
        const int boff_ = (buf) * 16384;                                    \
        _Pragma("unroll") for (int kk = 0; kk < 2; ++kk) {                  \
            bf16x8 a0_ = *(const bf16x8*)(smem + boff_ + raddrA[kk][0]);    \
            bf16x8 a1_ = *(const bf16x8*)(smem + boff_ + raddrA[kk][1]);    \
            bf16x8 b0_ = *(const bf16x8*)(smem + boff_ + raddrB[kk]);       \
            acc[0] = __builtin_amdgcn_mfma_f32_32x32x16_bf16(a0_, b0_, acc[0], 0, 0, 0); \
            acc[1] = __builtin_amdgcn_mfma_f32_32x32x16_bf16(a1_, b0_, acc[1], 0, 0, 0); \
        }                                                                   \
    }

    // Prologue: issue loads for tile 0.
    LOAD_TILE(0);

    for (int k = 0; k < NK; ++k) {
        WRITE_TILE(k & 1);            // vmcnt wait lands here (issued a full iter ago)
        if (k + 1 < NK) LOAD_TILE(k + 1);
        __syncthreads();              // staged tile visible to all waves
        COMPUTE(k & 1);
        // W(k+1) overwrites buf (k+1)&1, last read in COMPUTE(k-1);
        // barrier(k) sits between them -> single barrier per iter is safe.
    }

#undef LOAD_TILE
#undef WRITE_TILE
#undef COMPUTE

    // Epilogue. C/D layout (HW-verified): col = lane&31, row = (r&3)+8*(r>>2)+4*(lane>>5).
    const int s_w = mt * 128 + wm * 64;
    const int ccol = nt * 128 + wn * 32 + lm;
    float* outp = out + BC;   // skip leftmost row
#pragma unroll
    for (int m2 = 0; m2 < 2; ++m2) {
#pragma unroll
        for (int r = 0; r < 16; ++r) {
            const int row  = (r & 3) + 8 * (r >> 2) + 4 * kg;
            const int srow = s_w + m2 * 32 + row;
            outp[(size_t)srow * BC + b * C + ccol] = acc[m2][r];
        }
    }
}

extern "C" void kernel_launch(void* const* d_in, const int* in_sizes, int n_in,
                              void* d_out, int out_size, void* d_ws, size_t ws_size,
                              hipStream_t stream) {
    const float* x    = (const float*)d_in[0];  // [T,B,C] fp32
    const float* mask = (const float*)d_in[1];  // [B,T,S] fp32
    // d_in[2] = size_of_groups (int64) — unused by the 'average' reference path
    const float* left = (const float*)d_in[3];  // [1,1,C] fp32
    float* out = (float*)d_out;                 // [S+1,B,C] fp32

    left_fill<<<BC / 256, 256, 0, stream>>>(left, out);
    ds_gemm<<<Bb * (S / 128) * (C / 128), 512, 0, stream>>>(x, mask, out);
}

// Round 5
// 157.870 us; speedup vs baseline: 3.3164x; 1.0184x over previous
//
#include <hip/hip_runtime.h>
#include <hip/hip_bf16.h>

// Problem constants (fixed by the reference).
constexpr int T  = 4096;   // contraction dim (K = t)
constexpr int Bb = 8;      // batch
constexpr int C  = 512;    // channels (N)
constexpr int S  = 2048;   // groups (M)
constexpr int BC = Bb * C; // 4096 floats: t-row stride of x, s-row stride of out

constexpr int BK = 32;        // K-tile staged per iteration
constexpr int NK = T / BK;    // 128 iterations

typedef __bf16 bf16x8 __attribute__((ext_vector_type(8)));
typedef float  f32x16 __attribute__((ext_vector_type(16)));
typedef float  f32x4  __attribute__((ext_vector_type(4)));

// pack two f32 -> one dword of 2x bf16 (lo = first, hi = second), RNE.
__device__ inline unsigned pk2(float lo, float hi) {
    union { __hip_bfloat16 h; unsigned short u; } a, b;
    a.h = __float2bfloat16(lo);
    b.h = __float2bfloat16(hi);
    return ((unsigned)b.u << 16) | (unsigned)a.u;
}

// 16B-slot swizzle, bijective within each 32-slot group; spreads the
// stride-4-slot staging writes across all 8 bank quads while fragment
// reads stay a lane-permuted contiguous 512B region (conflict-free).
__device__ inline int slot16(int s) { return s ^ ((s >> 2) & 7); }

// out[0,b,c] = leftmost[c]
__global__ void left_fill(const float* __restrict__ left, float* __restrict__ out) {
    int i = blockIdx.x * blockDim.x + threadIdx.x;   // 0..BC-1
    if (i < BC) out[i] = left[i & (C - 1)];
}

// Per-b GEMM: out[(s+1),b,c] = sum_t mask[b,t,s] * x[t,b,c].
// Block 256 thr = 4 waves (2m x 2n), tile 128(s) x 128(c), wave tile 64x64,
// K-tile 32, dbuf LDS (32KB) -> 4 blocks/CU = 16 waves/CU with 4 independent
// HBM load streams. Loop (validated round 4): W(k)[vmcnt wait] -> issue
// loads(k+1) -> barrier -> COMPUTE(k): loads get a full iteration of cover.
// LDS (bf16) per operand per buf: oct(t/8)*2048B + slot16(col)*16B + (t&7)*2B
// -> one ds_read_b128 per 32x32x16 fragment operand; 1:1 read:MFMA ratio.
__global__ __launch_bounds__(256, 4) void ds_gemm(
    const float* __restrict__ x,
    const float* __restrict__ mask,
    float* __restrict__ out)
{
    __shared__ __align__(16) unsigned char smem[32768];  // 2 bufs x (8KB A | 8KB B)

    const int bid = blockIdx.x;
    const int mt  = bid & 15;        // s-tile (fastest)
    const int nt  = (bid >> 4) & 3;  // c-tile
    const int b   = bid >> 6;        // batch (slowest)

    const int tid  = threadIdx.x;
    const int lane = tid & 63;
    const int wave = tid >> 6;       // 0..3
    const int wm = wave >> 1;        // s-half (0..1)
    const int wn = wave & 1;         // c-half (0..1)
    const int lm = lane & 31;
    const int kg = lane >> 5;

    // ---------------- staging role: threads 0-127 stage A(mask), 128-255 B(x)
    // Each thread: one t-oct (8 rows) x 4 cols -> 8 global f32x4 loads,
    // pack to 4x ds_write_b128 (8 bf16 t-values per col slot).
    const int  ii  = tid & 127;
    const int  sg  = ii & 31;        // 4-wide col group within 128-wide tile
    const int  tg  = ii >> 5;        // t-oct 0..3 within the K-tile
    const bool stB = (tid >= 128);

    const float* gsrc = stB
        ? x    + (size_t)(tg * 8) * BC + b * C + nt * 128 + sg * 4
        : mask + (size_t)b * T * S + (size_t)(tg * 8) * S + mt * 128 + sg * 4;
    const size_t grow  = stB ? (size_t)BC : (size_t)S;  // floats per t-row
    const size_t gstep = grow * BK;                      // advance per K-tile

    int waddr[4];
#pragma unroll
    for (int j = 0; j < 4; ++j)
        waddr[j] = (stB ? 8192 : 0) + tg * 2048 + slot16(sg * 4 + j) * 16;

    // ---------------- fragment read addresses (oct = kk*2 + kg)
    int raddrA[2][2], raddrB[2][2];
#pragma unroll
    for (int kk = 0; kk < 2; ++kk)
#pragma unroll
        for (int q = 0; q < 2; ++q) {
            raddrA[kk][q] = (kk * 2 + kg) * 2048 + slot16(wm * 64 + q * 32 + lm) * 16;
            raddrB[kk][q] = 8192 + (kk * 2 + kg) * 2048 + slot16(wn * 64 + q * 32 + lm) * 16;
        }

    f32x16 acc[2][2] = {};
    f32x4  L[8];

#define LOAD_TILE(k)                                                        \
    {                                                                       \
        const float* p_ = gsrc + (size_t)(k) * gstep;                       \
        _Pragma("unroll") for (int r = 0; r < 8; ++r)                       \
            L[r] = *(const f32x4*)(p_ + (size_t)r * grow);                  \
    }

#define WRITE_TILE(buf)                                                     \
    {                                                                       \
        const int boff_ = (buf) * 16384;                                    \
        _Pragma("unroll") for (int j = 0; j < 4; ++j) {                     \
            uint4 w_;                                                       \
            w_.x = pk2(L[0][j], L[1][j]);                                   \
            w_.y = pk2(L[2][j], L[3][j]);                                   \
            w_.z = pk2(L[4][j], L[5][j]);                                   \
            w_.w = pk2(L[6][j], L[7][j]);                                   \
            *(uint4*)(smem + boff_ + waddr[j]) = w_;                        \
        }                                                                   \
    }

#define COMPUTE(buf)                                                        \
    {                                                                       \
        const int boff_ = (buf) * 16384;                                    \
        _Pragma("unroll") for (int kk = 0; kk < 2; ++kk) {                  \
            bf16x8 a0_ = *(const bf16x8*)(smem + boff_ + raddrA[kk][0]);    \
            bf16x8 a1_ = *(const bf16x8*)(smem + boff_ + raddrA[kk][1]);    \
            bf16x8 b0_ = *(const bf16x8*)(smem + boff_ + raddrB[kk][0]);    \
            bf16x8 b1_ = *(const bf16x8*)(smem + boff_ + raddrB[kk][1]);    \
            acc[0][0] = __builtin_amdgcn_mfma_f32_32x32x16_bf16(a0_, b0_, acc[0][0], 0, 0, 0); \
            acc[0][1] = __builtin_amdgcn_mfma_f32_32x32x16_bf16(a0_, b1_, acc[0][1], 0, 0, 0); \
            acc[1][0] = __builtin_amdgcn_mfma_f32_32x32x16_bf16(a1_, b0_, acc[1][0], 0, 0, 0); \
            acc[1][1] = __builtin_amdgcn_mfma_f32_32x32x16_bf16(a1_, b1_, acc[1][1], 0, 0, 0); \
        }                                                                   \
    }

    // Prologue: issue loads for tile 0.
    LOAD_TILE(0);

    for (int k = 0; k < NK; ++k) {
        WRITE_TILE(k & 1);            // vmcnt wait lands here (issued a full iter ago)
        if (k + 1 < NK) LOAD_TILE(k + 1);
        __syncthreads();              // staged tile visible to all waves
        COMPUTE(k & 1);
        // W(k+1) overwrites buf (k+1)&1, last read in COMPUTE(k-1);
        // barrier(k) sits between them -> single barrier per iter is safe.
    }

#undef LOAD_TILE
#undef WRITE_TILE
#undef COMPUTE

    // Epilogue. C/D layout (HW-verified): col = lane&31, row = (r&3)+8*(r>>2)+4*(lane>>5).
    const int s_w = mt * 128 + wm * 64;
    const int c_w = nt * 128 + wn * 64;
    float* outp = out + BC;   // skip leftmost row
#pragma unroll
    for (int m2 = 0; m2 < 2; ++m2) {
#pragma unroll
        for (int n2 = 0; n2 < 2; ++n2) {
#pragma unroll
            for (int r = 0; r < 16; ++r) {
                const int row  = (r & 3) + 8 * (r >> 2) + 4 * kg;
                const int srow = s_w + m2 * 32 + row;
                const int ccol = c_w + n2 * 32 + lm;
                outp[(size_t)srow * BC + b * C + ccol] = acc[m2][n2][r];
            }
        }
    }
}

extern "C" void kernel_launch(void* const* d_in, const int* in_sizes, int n_in,
                              void* d_out, int out_size, void* d_ws, size_t ws_size,
                              hipStream_t stream) {
    const float* x    = (const float*)d_in[0];  // [T,B,C] fp32
    const float* mask = (const float*)d_in[1];  // [B,T,S] fp32
    // d_in[2] = size_of_groups (int64) — unused by the 'average' reference path
    const float* left = (const float*)d_in[3];  // [1,1,C] fp32
    float* out = (float*)d_out;                 // [S+1,B,C] fp32

    left_fill<<<BC / 256, 256, 0, stream>>>(left, out);
    ds_gemm<<<Bb * (S / 128) * (C / 128), 256, 0, stream>>>(x, mask, out);
}